// Round 12
// baseline (192.546 us; speedup 1.0000x reference)
//
#include <hip/hip_runtime.h>
#include <hip/hip_bf16.h>
#include <hip/hip_fp8.h>
#include <stdint.h>

#define B_   64
#define L_   512
#define E_   256
#define P_   64
#define KOUT 512
#define KS_  3
#define H_   512
#define T_   53
#define CINW 2688           // conv_w inner: 896*3
#define LE   516            // embp rows/batch: L + 4 (2 zero each side)
#define LPP  514            // posp rows/batch: L + 2 (1 zero each side)
#define COMW 2048           // 1536 ent + 512 sent_h

// fp8 uniform scaling: data x64, weights x64, accumulator /4096
#define FP8_S    64.0f
#define DESCALE  (1.0f / 4096.0f)

// prep-kernel grid sections
#define SEC_CW    0
#define SEC_EMBP  512
#define SEC_POSP  (SEC_EMBP + (B_ * LE / 4))     // 512 + 8256 = 8768
#define SEC_ENT   (SEC_POSP + (B_ * LPP / 4))    // 8768 + 8224 = 16992
#define SEC_POOL  (SEC_ENT + 2 * B_)             // 16992 + 128 = 17120
#define SEC_END   (SEC_POOL + 32)                // 17152

typedef __attribute__((ext_vector_type(4))) float f32x4;
typedef __attribute__((ext_vector_type(2))) long longx2;

__device__ __forceinline__ unsigned enc_f(float x) {
    unsigned u = __float_as_uint(x);
    return (u & 0x80000000u) ? ~u : (u | 0x80000000u);
}
__device__ __forceinline__ float dec_f(unsigned e) {
    return __uint_as_float((e & 0x80000000u) ? (e & 0x7fffffffu) : ~e);
}
__device__ __forceinline__ unsigned char f8c(float x) {
    __hip_fp8_e4m3 t(x);            // OCP e4m3fn (gfx950) — NOT fnuz
    return t.__x;
}

// K-granule interleave within each 64B chunk: stored granule s holds original
// granule perm[s]=[0,4,1,5,2,6,3,7][s]. A 16B read at chunk q then yields
// k=[8q..8q+7] (low 8B, MFMA h=0) and k=[32+8q..+7] (high 8B, h=1).
// Index map for writers (orig byte c -> stored byte):
__device__ __forceinline__ int kperm(int c) {
    int g = (c >> 3) & 7;                        // orig granule within chunk
    return (c & ~63) | ((2 * (g & 3) + (g >> 2)) * 8) | (c & 7);
}

__device__ __forceinline__ void cp16(const void* g, void* l) {
    __builtin_amdgcn_global_load_lds(
        (const __attribute__((address_space(1))) unsigned int*)g,
        (__attribute__((address_space(3))) unsigned int*)l,
        16, 0, 0);
}

// ---------------------------------------------------------------------------
// Fused prep: 5 independent jobs selected by blockIdx.x section.
__global__ void prep(const float* __restrict__ conv_w,
                     const int* __restrict__ context,
                     const int* __restrict__ sidx,
                     const int* __restrict__ oidx,
                     const int* __restrict__ sdis,
                     const int* __restrict__ odis,
                     const float* __restrict__ etab,
                     const float* __restrict__ ptab,
                     unsigned char* __restrict__ wce,     // fp8, x64, k-interleaved
                     unsigned char* __restrict__ wcp,     // fp8, x64, k-interleaved
                     __hip_bfloat16* __restrict__ wcorr,  // bf16, exact path
                     unsigned char* __restrict__ embp,    // fp8, x64, k-interleaved
                     unsigned char* __restrict__ posp,    // fp8, x64, k-interleaved
                     float* __restrict__ com,
                     unsigned* __restrict__ pooled) {
    __shared__ float w[CINW];
    const int blk = blockIdx.x;
    const int tid = threadIdx.x;

    if (blk < SEC_EMBP) {
        // ---- combine_w: one block per output channel n ----
        int n = blk;
        const float* src = conv_w + (size_t)n * CINW;
        for (int i = tid; i < CINW; i += 256) w[i] = src[i];
        __syncthreads();
        for (int i = tid; i < 5 * E_; i += 256) {
            int d = i >> 8, c = i & 255;
            float s = 0.f;
#pragma unroll
            for (int tau = 0; tau <= 2; tau++) {
                int seg = d - tau;
                if (seg >= 0 && seg <= 2) s += w[(seg * 256 + c) * 3 + tau];
            }
            wce[((size_t)d * KOUT + n) * E_ + kperm(c)] = f8c(s * FP8_S);
        }
        for (int i = tid; i < 3 * 128; i += 256) {
            int tau = i >> 7, p = i & 127;
            wcp[((size_t)tau * KOUT + n) * 128 + kperm(p)] = f8c(w[(768 + p) * 3 + tau] * FP8_S);
        }
        for (int i = tid; i < 2 * E_; i += 256) {
            int which = i >> 8, c = i & 255;
            wcorr[((size_t)which * KOUT + n) * E_ + c] =
                __float2bfloat16(which ? w[c * 3 + 2] : w[(512 + c) * 3 + 0]);
        }
    } else if (blk < SEC_POSP) {
        // ---- build_embp (fp8 x64, k-interleaved) ----
        int row = (blk - SEC_EMBP) * 4 + (tid >> 6);
        int lane = tid & 63;
        int b = row / LE, r = row % LE;
        unsigned char* out = embp + (size_t)row * E_;
        int spos = kperm(lane * 4);              // 4B-aligned (bijective over row)
        if (r < 2 || r >= LE - 2) {
            *(uchar4*)(out + spos) = (uchar4){0, 0, 0, 0};
            return;
        }
        int token = context[b * L_ + (r - 2)];
        float4 v = *(const float4*)(etab + (size_t)token * E_ + lane * 4);
        uchar4 pk;
        pk.x = f8c(v.x * FP8_S); pk.y = f8c(v.y * FP8_S);
        pk.z = f8c(v.z * FP8_S); pk.w = f8c(v.w * FP8_S);
        *(uchar4*)(out + spos) = pk;
    } else if (blk < SEC_ENT) {
        // ---- build_posp (fp8 x64, k-interleaved) ----
        int row = (blk - SEC_POSP) * 4 + (tid >> 6);
        int lane = tid & 63;
        int b = row / LPP, r = row % LPP;
        unsigned char* out = posp + (size_t)row * 128;
        int which = lane >> 5;
        int i2 = (lane & 31) * 2;
        int spos = kperm(which * 64 + i2);       // 2B-aligned
        if (r < 1 || r >= LPP - 1) {
            *(unsigned short*)(out + spos) = 0;
            return;
        }
        int l = r - 1;
        int t = which ? odis[b * L_ + l] : sdis[b * L_ + l];
        float2 v = *(const float2*)(ptab + (size_t)t * P_ + i2);
        unsigned short pk = (unsigned short)f8c(v.x * FP8_S)
                          | ((unsigned short)f8c(v.y * FP8_S) << 8);
        *(unsigned short*)(out + spos) = pk;
    } else if (blk < SEC_POOL) {
        // ---- entity_feats (fp32 exact) ----
        int idx = blk - SEC_ENT;
        int b = idx >> 1, which = idx & 1;
        const int* sp = which ? oidx : sidx;
        int s = sp[b * 2 + 0], e = sp[b * 2 + 1];
        const int* ctx = context + b * L_;
        float* outb = com + (size_t)b * COMW + which * 768;
        int d = tid;
        float sum = 0.f;
        for (int x = s; x <= e; ++x) sum += etab[(size_t)ctx[x] * E_ + d];
        outb[d] = sum / (float)(e - s + 1);
        outb[256 + d] = etab[(size_t)ctx[s - 1] * E_ + d];
        float r = 0.f;
        if (e + 1 < L_) r = etab[(size_t)ctx[e + 1] * E_ + d];
        outb[512 + d] = r;
    } else {
        // ---- zero pooled ----
        int base = ((blk - SEC_POOL) * 256 + tid) * 4;
        *(uint4*)(pooled + base) = (uint4){0, 0, 0, 0};
    }
}

// ---------------------------------------------------------------------------
// Edge-correction (fp32-exact): corr[b][which][n] = emb_edge . wcorr[which][n]
__global__ void corr_k(const int* __restrict__ ctx,
                       const float* __restrict__ etab,
                       const __hip_bfloat16* __restrict__ wcorr,
                       float* __restrict__ corr) {
    int wid = blockIdx.x * 4 + (threadIdx.x >> 6);
    int lane = threadIdx.x & 63;
    int n4    = wid & 127;
    int which = (wid >> 7) & 1;
    int b     = wid >> 8;
    int token = ctx[b * L_ + (which ? L_ - 1 : 0)];
    float4 ev = *(const float4*)(etab + (size_t)token * E_ + lane * 4);
#pragma unroll
    for (int k = 0; k < 4; k++) {
        int n = n4 * 4 + k;
        const __hip_bfloat16* wr = wcorr + ((size_t)which * KOUT + n) * E_ + lane * 4;
        float s = ev.x * __bfloat162float(wr[0]) + ev.y * __bfloat162float(wr[1])
                + ev.z * __bfloat162float(wr[2]) + ev.w * __bfloat162float(wr[3]);
#pragma unroll
        for (int off = 32; off > 0; off >>= 1) s += __shfl_down(s, off, 64);
        if (lane == 0) corr[(b * 2 + which) * KOUT + n] = s;
    }
}

// ---------------------------------------------------------------------------
// fp8 conv GEMM + fused maxpool + edge corr. K-interleaved buffers make each
// 16B LDS read serve both K=32 MFMA halves -> b128 reads at the bf16 kernel's
// verified 0-conflict addresses (R11's b64 path was 4-way conflicted, 6.8e6).
// 16 KB LDS, 26 barrier pairs, occupancy preserved.
__global__ void conv_gemm_pool(const unsigned char* __restrict__ embp,
                               const unsigned char* __restrict__ posp,
                               const unsigned char* __restrict__ wce,
                               const unsigned char* __restrict__ wcp,
                               const float* __restrict__ corr,
                               unsigned* __restrict__ pooled) {
    __shared__ unsigned char sA[128 * 64];   // 8 KB: 128 rows x 64B (64 fp8 K)
    __shared__ unsigned char sB[128 * 64];   // 8 KB

    const int tid  = threadIdx.x;
    const int wave = tid >> 6;
    const int lane = tid & 63;
    const int mt = blockIdx.x;
    const int nt = blockIdx.y;
    const int b  = mt >> 2;
    const int l0 = (mt & 3) * 128;
    const int n0 = nt * 128;

    const int wr = (wave & 1) * 64;
    const int wc = (wave >> 1) * 64;
    const int m  = lane & 15;
    const int q  = lane >> 4;

    f32x4 acc[4][4];
#pragma unroll
    for (int i = 0; i < 4; i++)
#pragma unroll
        for (int j = 0; j < 4; j++) acc[i][j] = (f32x4){0.f, 0.f, 0.f, 0.f};

    const int rowA = tid >> 2;                             // staging row
    const int cswz = ((tid & 3) ^ ((tid >> 3) & 3)) * 16;  // 16B-chunk XOR swizzle
    const int rsw  = (q ^ ((m >> 1) & 3)) * 16;            // read-side chunk swizzle

    auto step = [&](const char* Ab, int AsB, const char* Bb, int BsB) {
        cp16(Ab + rowA * AsB + cswz, (char*)sA + tid * 16);
        cp16(Bb + rowA * BsB + cswz, (char*)sB + tid * 16);
        cp16(Ab + (rowA + 64) * AsB + cswz, (char*)sA + (tid + 256) * 16);
        cp16(Bb + (rowA + 64) * BsB + cswz, (char*)sB + (tid + 256) * 16);
        __syncthreads();
        longx2 af[4], bfr[4];
#pragma unroll
        for (int i = 0; i < 4; i++)
            af[i] = *(const longx2*)((const char*)sA + (wr + i * 16 + m) * 64 + rsw);
#pragma unroll
        for (int j = 0; j < 4; j++)
            bfr[j] = *(const longx2*)((const char*)sB + (wc + j * 16 + m) * 64 + rsw);
#pragma unroll
        for (int i = 0; i < 4; i++)
#pragma unroll
            for (int j = 0; j < 4; j++)
                acc[i][j] = __builtin_amdgcn_mfma_f32_16x16x32_fp8_fp8(
                    af[i].x, bfr[j].x, acc[i][j], 0, 0, 0);
#pragma unroll
        for (int i = 0; i < 4; i++)
#pragma unroll
            for (int j = 0; j < 4; j++)
                acc[i][j] = __builtin_amdgcn_mfma_f32_16x16x32_fp8_fp8(
                    af[i].y, bfr[j].y, acc[i][j], 0, 0, 0);
        __syncthreads();
    };

    // emb phase: 5 taps x 4 chunks of 64 fp8 elems
    for (int t = 0; t < 5; t++) {
        const char* Abase = (const char*)(embp + (size_t)(b * LE + l0 + t) * E_);
        const char* Bbase = (const char*)(wce + (size_t)(t * KOUT + n0) * E_);
        for (int kc = 0; kc < E_; kc += 64)
            step(Abase + kc, E_, Bbase + kc, E_);
    }
    // pos phase: 3 taps x 2 chunks
    for (int t = 0; t < 3; t++) {
        const char* Abase = (const char*)(posp + (size_t)(b * LPP + l0 + t) * 128);
        const char* Bbase = (const char*)(wcp + (size_t)(t * KOUT + n0) * 128);
        for (int kc = 0; kc < 128; kc += 64)
            step(Abase + kc, 128, Bbase + kc, 128);
    }

    const float* corrb = corr + b * 2 * KOUT;
#pragma unroll
    for (int j = 0; j < 4; j++) {
        int col = n0 + wc + j * 16 + m;
        float mx = -3.4e38f;
#pragma unroll
        for (int i = 0; i < 4; i++)
#pragma unroll
            for (int r = 0; r < 4; r++) {
                float v = acc[i][j][r] * DESCALE;
                int l = l0 + wr + i * 16 + q * 4 + r;
                if (l == 0)      v -= corrb[col];
                if (l == L_ - 1) v -= corrb[KOUT + col];
                mx = fmaxf(mx, v);
            }
        mx = fmaxf(mx, __shfl_xor(mx, 16, 64));
        mx = fmaxf(mx, __shfl_xor(mx, 32, 64));
        if (q == 0) atomicMax(&pooled[b * KOUT + col], enc_f(mx));
    }
}

// ---------------------------------------------------------------------------
__global__ void lin1_k(const unsigned* __restrict__ pooled,
                       const float* __restrict__ conv_b,
                       const float* __restrict__ lin1_w,
                       const float* __restrict__ lin1_b,
                       float* __restrict__ com) {
    int bid = blockIdx.x;
    int wave = threadIdx.x >> 6, lane = threadIdx.x & 63;
    int b = bid >> 7;
    int h = (bid & 127) * 4 + wave;
    const float* w = lin1_w + (size_t)h * KOUT;
    const unsigned* pb = pooled + b * KOUT;
    float s = 0.f;
#pragma unroll
    for (int i = 0; i < 8; i++) {
        int k = lane + 64 * i;
        s += (dec_f(pb[k]) + conv_b[k]) * w[k];
    }
#pragma unroll
    for (int off = 32; off > 0; off >>= 1) s += __shfl_down(s, off, 64);
    if (lane == 0) com[(size_t)b * COMW + 1536 + h] = tanhf(s + lin1_b[h]);
}

__global__ void lin2_k(const float* __restrict__ com,
                       const float* __restrict__ lin2_w,
                       const float* __restrict__ lin2_b,
                       float* __restrict__ out) {
    int b = blockIdx.x;
    int wave = threadIdx.x >> 6, lane = threadIdx.x & 63;
    int t = blockIdx.y * 4 + wave;
    if (t >= T_) return;
    const float* w = lin2_w + (size_t)t * COMW;
    const float* c = com + (size_t)b * COMW;
    float s = 0.f;
#pragma unroll
    for (int i = 0; i < 32; i++) {
        int k = lane + 64 * i;
        s += c[k] * w[k];
    }
#pragma unroll
    for (int off = 32; off > 0; off >>= 1) s += __shfl_down(s, off, 64);
    if (lane == 0) out[b * T_ + t] = s + lin2_b[t];
}

// ---------------------------------------------------------------------------
extern "C" void kernel_launch(void* const* d_in, const int* in_sizes, int n_in,
                              void* d_out, int out_size, void* d_ws, size_t ws_size,
                              hipStream_t stream) {
    const int*   context = (const int*)d_in[0];
    const int*   sidx    = (const int*)d_in[1];
    const int*   oidx    = (const int*)d_in[2];
    const int*   sdis    = (const int*)d_in[3];
    const int*   odis    = (const int*)d_in[4];
    const float* etab    = (const float*)d_in[5];
    const float* ptab    = (const float*)d_in[6];
    const float* conv_w  = (const float*)d_in[7];
    const float* conv_b  = (const float*)d_in[8];
    const float* lin1_w  = (const float*)d_in[9];
    const float* lin1_b  = (const float*)d_in[10];
    const float* lin2_w  = (const float*)d_in[11];
    const float* lin2_b  = (const float*)d_in[12];
    float* out = (float*)d_out;

    char* ws = (char*)d_ws;
    size_t off = 0;
    unsigned char* embp = (unsigned char*)(ws + off);
    off += (size_t)B_ * LE * E_;                 // 8.45 MB (fp8)
    off = (off + 255) & ~(size_t)255;
    unsigned char* posp = (unsigned char*)(ws + off);
    off += (size_t)B_ * LPP * 128;               // 4.2 MB (fp8)
    off = (off + 255) & ~(size_t)255;
    unsigned char* wce = (unsigned char*)(ws + off);
    off += (size_t)5 * KOUT * E_;                // 655 KB (fp8)
    off = (off + 255) & ~(size_t)255;
    unsigned char* wcp = (unsigned char*)(ws + off);
    off += (size_t)3 * KOUT * 128;               // 197 KB (fp8)
    off = (off + 255) & ~(size_t)255;
    __hip_bfloat16* wcorr = (__hip_bfloat16*)(ws + off);
    off += (size_t)2 * KOUT * E_ * 2;            // 0.5 MB
    off = (off + 255) & ~(size_t)255;
    float* corr = (float*)(ws + off);
    off += (size_t)B_ * 2 * KOUT * 4;            // 256 KB
    off = (off + 255) & ~(size_t)255;
    unsigned* pooled = (unsigned*)(ws + off);
    off += (size_t)B_ * KOUT * 4;                // 128 KB
    off = (off + 255) & ~(size_t)255;
    float* com = (float*)(ws + off);
    off += (size_t)B_ * COMW * 4;                // 512 KB

    prep<<<dim3(SEC_END), dim3(256), 0, stream>>>(
        conv_w, context, sidx, oidx, sdis, odis, etab, ptab,
        wce, wcp, wcorr, embp, posp, com, pooled);
    corr_k<<<dim3(4096), dim3(256), 0, stream>>>(context, etab, wcorr, corr);
    conv_gemm_pool<<<dim3(256, 4), dim3(256), 0, stream>>>(embp, posp, wce, wcp, corr, pooled);
    lin1_k<<<dim3(8192), dim3(256), 0, stream>>>(pooled, conv_b, lin1_w, lin1_b, com);
    lin2_k<<<dim3(B_, 14), dim3(256), 0, stream>>>(com, lin2_w, lin2_b, out);
}

// Round 13
// 189.493 us; speedup vs baseline: 1.0161x; 1.0161x over previous
//
#include <hip/hip_runtime.h>
#include <hip/hip_bf16.h>
#include <hip/hip_fp8.h>
#include <stdint.h>

#define B_   64
#define L_   512
#define E_   256
#define P_   64
#define KOUT 512
#define KS_  3
#define H_   512
#define T_   53
#define CINW 2688           // conv_w inner: 896*3
#define LE   516            // embp rows/batch: L + 4 (2 zero each side)
#define LPP  514            // posp rows/batch: L + 2 (1 zero each side)
#define COMW 2048           // 1536 ent + 512 sent_h

// fp8 uniform scaling: data x64, weights x64, accumulator /4096
#define FP8_S    64.0f
#define DESCALE  (1.0f / 4096.0f)

// prep-kernel grid sections
#define SEC_CW    0
#define SEC_EMBP  512
#define SEC_POSP  (SEC_EMBP + (B_ * LE / 4))     // 512 + 8256 = 8768
#define SEC_ENT   (SEC_POSP + (B_ * LPP / 4))    // 8768 + 8224 = 16992
#define SEC_POOL  (SEC_ENT + 2 * B_)             // 16992 + 128 = 17120
#define SEC_END   (SEC_POOL + 32)                // 17152

typedef __attribute__((ext_vector_type(4))) float f32x4;

__device__ __forceinline__ unsigned enc_f(float x) {
    unsigned u = __float_as_uint(x);
    return (u & 0x80000000u) ? ~u : (u | 0x80000000u);
}
__device__ __forceinline__ float dec_f(unsigned e) {
    return __uint_as_float((e & 0x80000000u) ? (e & 0x7fffffffu) : ~e);
}
__device__ __forceinline__ unsigned char f8c(float x) {
    __hip_fp8_e4m3 t(x);            // OCP e4m3fn (gfx950) — NOT fnuz
    return t.__x;
}

__device__ __forceinline__ void cp16(const void* g, void* l) {
    __builtin_amdgcn_global_load_lds(
        (const __attribute__((address_space(1))) unsigned int*)g,
        (__attribute__((address_space(3))) unsigned int*)l,
        16, 0, 0);
}

// ---------------------------------------------------------------------------
// Fused prep: 5 independent jobs selected by blockIdx.x section.
__global__ void prep(const float* __restrict__ conv_w,
                     const int* __restrict__ context,
                     const int* __restrict__ sidx,
                     const int* __restrict__ oidx,
                     const int* __restrict__ sdis,
                     const int* __restrict__ odis,
                     const float* __restrict__ etab,
                     const float* __restrict__ ptab,
                     unsigned char* __restrict__ wce,     // fp8, x64
                     unsigned char* __restrict__ wcp,     // fp8, x64
                     __hip_bfloat16* __restrict__ wcorr,  // bf16, exact path
                     unsigned char* __restrict__ embp,    // fp8, x64
                     unsigned char* __restrict__ posp,    // fp8, x64
                     float* __restrict__ com,
                     unsigned* __restrict__ pooled) {
    __shared__ float w[CINW];
    const int blk = blockIdx.x;
    const int tid = threadIdx.x;

    if (blk < SEC_EMBP) {
        // ---- combine_w: one block per output channel n ----
        int n = blk;
        const float* src = conv_w + (size_t)n * CINW;
        for (int i = tid; i < CINW; i += 256) w[i] = src[i];
        __syncthreads();
        for (int i = tid; i < 5 * E_; i += 256) {
            int d = i >> 8, c = i & 255;
            float s = 0.f;
#pragma unroll
            for (int tau = 0; tau <= 2; tau++) {
                int seg = d - tau;
                if (seg >= 0 && seg <= 2) s += w[(seg * 256 + c) * 3 + tau];
            }
            wce[((size_t)d * KOUT + n) * E_ + c] = f8c(s * FP8_S);
        }
        for (int i = tid; i < 3 * 128; i += 256) {
            int tau = i >> 7, p = i & 127;
            wcp[((size_t)tau * KOUT + n) * 128 + p] = f8c(w[(768 + p) * 3 + tau] * FP8_S);
        }
        for (int i = tid; i < 2 * E_; i += 256) {
            int which = i >> 8, c = i & 255;
            wcorr[((size_t)which * KOUT + n) * E_ + c] =
                __float2bfloat16(which ? w[c * 3 + 2] : w[(512 + c) * 3 + 0]);
        }
    } else if (blk < SEC_POSP) {
        // ---- build_embp (fp8 x64) ----
        int row = (blk - SEC_EMBP) * 4 + (tid >> 6);
        int lane = tid & 63;
        int b = row / LE, r = row % LE;
        unsigned char* out = embp + (size_t)row * E_;
        if (r < 2 || r >= LE - 2) {
            *(uchar4*)(out + lane * 4) = (uchar4){0, 0, 0, 0};
            return;
        }
        int token = context[b * L_ + (r - 2)];
        float4 v = *(const float4*)(etab + (size_t)token * E_ + lane * 4);
        uchar4 pk;
        pk.x = f8c(v.x * FP8_S); pk.y = f8c(v.y * FP8_S);
        pk.z = f8c(v.z * FP8_S); pk.w = f8c(v.w * FP8_S);
        *(uchar4*)(out + lane * 4) = pk;
    } else if (blk < SEC_ENT) {
        // ---- build_posp (fp8 x64) ----
        int row = (blk - SEC_POSP) * 4 + (tid >> 6);
        int lane = tid & 63;
        int b = row / LPP, r = row % LPP;
        unsigned char* out = posp + (size_t)row * 128;
        if (r < 1 || r >= LPP - 1) {
            *(unsigned short*)(out + lane * 2) = 0;
            return;
        }
        int l = r - 1;
        int which = lane >> 5;
        int i2 = (lane & 31) * 2;
        int t = which ? odis[b * L_ + l] : sdis[b * L_ + l];
        float2 v = *(const float2*)(ptab + (size_t)t * P_ + i2);
        unsigned short pk = (unsigned short)f8c(v.x * FP8_S)
                          | ((unsigned short)f8c(v.y * FP8_S) << 8);
        *(unsigned short*)(out + which * 64 + i2) = pk;
    } else if (blk < SEC_POOL) {
        // ---- entity_feats (fp32 exact) ----
        int idx = blk - SEC_ENT;
        int b = idx >> 1, which = idx & 1;
        const int* sp = which ? oidx : sidx;
        int s = sp[b * 2 + 0], e = sp[b * 2 + 1];
        const int* ctx = context + b * L_;
        float* outb = com + (size_t)b * COMW + which * 768;
        int d = tid;
        float sum = 0.f;
        for (int x = s; x <= e; ++x) sum += etab[(size_t)ctx[x] * E_ + d];
        outb[d] = sum / (float)(e - s + 1);
        outb[256 + d] = etab[(size_t)ctx[s - 1] * E_ + d];
        float r = 0.f;
        if (e + 1 < L_) r = etab[(size_t)ctx[e + 1] * E_ + d];
        outb[512 + d] = r;
    } else {
        // ---- zero pooled ----
        int base = ((blk - SEC_POOL) * 256 + tid) * 4;
        *(uint4*)(pooled + base) = (uint4){0, 0, 0, 0};
    }
}

// ---------------------------------------------------------------------------
// Edge-correction (fp32-exact): corr[b][which][n] = emb_edge . wcorr[which][n]
__global__ void corr_k(const int* __restrict__ ctx,
                       const float* __restrict__ etab,
                       const __hip_bfloat16* __restrict__ wcorr,
                       float* __restrict__ corr) {
    int wid = blockIdx.x * 4 + (threadIdx.x >> 6);
    int lane = threadIdx.x & 63;
    int n4    = wid & 127;
    int which = (wid >> 7) & 1;
    int b     = wid >> 8;
    int token = ctx[b * L_ + (which ? L_ - 1 : 0)];
    float4 ev = *(const float4*)(etab + (size_t)token * E_ + lane * 4);
#pragma unroll
    for (int k = 0; k < 4; k++) {
        int n = n4 * 4 + k;
        const __hip_bfloat16* wr = wcorr + ((size_t)which * KOUT + n) * E_ + lane * 4;
        float s = ev.x * __bfloat162float(wr[0]) + ev.y * __bfloat162float(wr[1])
                + ev.z * __bfloat162float(wr[2]) + ev.w * __bfloat162float(wr[3]);
#pragma unroll
        for (int off = 32; off > 0; off >>= 1) s += __shfl_down(s, off, 64);
        if (lane == 0) corr[(b * 2 + which) * KOUT + n] = s;
    }
}

// ---------------------------------------------------------------------------
// fp8 conv GEMM + fused maxpool + edge corr. R11 configuration — empirically
// optimal (45.4 us measured). NOTE (R12 post-mortem): the b64 two-half read
// carries an unavoidable 4-way LDS aliasing (128 words/32 banks) costing
// ~6.8e6 conflict cycles, but it is substantially hidden under the MFMA pipe;
// the b128 K-interleaved variant (R12) eliminated conflicts yet regressed
// 45.4->49.4 us (VGPR 56->64, +4MB conv FETCH). Keep this version.
__global__ void conv_gemm_pool(const unsigned char* __restrict__ embp,
                               const unsigned char* __restrict__ posp,
                               const unsigned char* __restrict__ wce,
                               const unsigned char* __restrict__ wcp,
                               const float* __restrict__ corr,
                               unsigned* __restrict__ pooled) {
    __shared__ unsigned char sA[128 * 64];   // 8 KB: 128 rows x 64B (64 fp8 K)
    __shared__ unsigned char sB[128 * 64];   // 8 KB

    const int tid  = threadIdx.x;
    const int wave = tid >> 6;
    const int lane = tid & 63;
    const int mt = blockIdx.x;
    const int nt = blockIdx.y;
    const int b  = mt >> 2;
    const int l0 = (mt & 3) * 128;
    const int n0 = nt * 128;

    const int wr = (wave & 1) * 64;
    const int wc = (wave >> 1) * 64;
    const int m  = lane & 15;
    const int q  = lane >> 4;

    f32x4 acc[4][4];
#pragma unroll
    for (int i = 0; i < 4; i++)
#pragma unroll
        for (int j = 0; j < 4; j++) acc[i][j] = (f32x4){0.f, 0.f, 0.f, 0.f};

    const int rowA = tid >> 2;                         // staging row (0..63, +64)
    const int cswz = ((tid & 3) ^ ((tid >> 3) & 3)) * 16;  // 16B-chunk XOR swizzle

    auto step = [&](const char* Ab, int AsB, const char* Bb, int BsB) {
        cp16(Ab + rowA * AsB + cswz, (char*)sA + tid * 16);
        cp16(Bb + rowA * BsB + cswz, (char*)sB + tid * 16);
        cp16(Ab + (rowA + 64) * AsB + cswz, (char*)sA + (tid + 256) * 16);
        cp16(Bb + (rowA + 64) * BsB + cswz, (char*)sB + (tid + 256) * 16);
        __syncthreads();
#pragma unroll
        for (int h = 0; h < 2; h++) {                  // two K=32 halves of the 64B row
            long af[4], bfr[4];
#pragma unroll
            for (int i = 0; i < 4; i++) {
                int row = wr + i * 16 + m;
                int pc = ((h << 1) | (q >> 1)) ^ ((row >> 1) & 3);
                af[i] = *(const long*)((const char*)sA + row * 64 + pc * 16 + (q & 1) * 8);
            }
#pragma unroll
            for (int j = 0; j < 4; j++) {
                int row = wc + j * 16 + m;
                int pc = ((h << 1) | (q >> 1)) ^ ((row >> 1) & 3);
                bfr[j] = *(const long*)((const char*)sB + row * 64 + pc * 16 + (q & 1) * 8);
            }
#pragma unroll
            for (int i = 0; i < 4; i++)
#pragma unroll
                for (int j = 0; j < 4; j++)
                    acc[i][j] = __builtin_amdgcn_mfma_f32_16x16x32_fp8_fp8(
                        af[i], bfr[j], acc[i][j], 0, 0, 0);
        }
        __syncthreads();
    };

    // emb phase: 5 taps x 4 chunks of 64 fp8 elems
    for (int t = 0; t < 5; t++) {
        const char* Abase = (const char*)(embp + (size_t)(b * LE + l0 + t) * E_);
        const char* Bbase = (const char*)(wce + (size_t)(t * KOUT + n0) * E_);
        for (int kc = 0; kc < E_; kc += 64)
            step(Abase + kc, E_, Bbase + kc, E_);
    }
    // pos phase: 3 taps x 2 chunks
    for (int t = 0; t < 3; t++) {
        const char* Abase = (const char*)(posp + (size_t)(b * LPP + l0 + t) * 128);
        const char* Bbase = (const char*)(wcp + (size_t)(t * KOUT + n0) * 128);
        for (int kc = 0; kc < 128; kc += 64)
            step(Abase + kc, 128, Bbase + kc, 128);
    }

    const float* corrb = corr + b * 2 * KOUT;
#pragma unroll
    for (int j = 0; j < 4; j++) {
        int col = n0 + wc + j * 16 + m;
        float mx = -3.4e38f;
#pragma unroll
        for (int i = 0; i < 4; i++)
#pragma unroll
            for (int r = 0; r < 4; r++) {
                float v = acc[i][j][r] * DESCALE;
                int l = l0 + wr + i * 16 + q * 4 + r;
                if (l == 0)      v -= corrb[col];
                if (l == L_ - 1) v -= corrb[KOUT + col];
                mx = fmaxf(mx, v);
            }
        mx = fmaxf(mx, __shfl_xor(mx, 16, 64));
        mx = fmaxf(mx, __shfl_xor(mx, 32, 64));
        if (q == 0) atomicMax(&pooled[b * KOUT + col], enc_f(mx));
    }
}

// ---------------------------------------------------------------------------
__global__ void lin1_k(const unsigned* __restrict__ pooled,
                       const float* __restrict__ conv_b,
                       const float* __restrict__ lin1_w,
                       const float* __restrict__ lin1_b,
                       float* __restrict__ com) {
    int bid = blockIdx.x;
    int wave = threadIdx.x >> 6, lane = threadIdx.x & 63;
    int b = bid >> 7;
    int h = (bid & 127) * 4 + wave;
    const float* w = lin1_w + (size_t)h * KOUT;
    const unsigned* pb = pooled + b * KOUT;
    float s = 0.f;
#pragma unroll
    for (int i = 0; i < 8; i++) {
        int k = lane + 64 * i;
        s += (dec_f(pb[k]) + conv_b[k]) * w[k];
    }
#pragma unroll
    for (int off = 32; off > 0; off >>= 1) s += __shfl_down(s, off, 64);
    if (lane == 0) com[(size_t)b * COMW + 1536 + h] = tanhf(s + lin1_b[h]);
}

__global__ void lin2_k(const float* __restrict__ com,
                       const float* __restrict__ lin2_w,
                       const float* __restrict__ lin2_b,
                       float* __restrict__ out) {
    int b = blockIdx.x;
    int wave = threadIdx.x >> 6, lane = threadIdx.x & 63;
    int t = blockIdx.y * 4 + wave;
    if (t >= T_) return;
    const float* w = lin2_w + (size_t)t * COMW;
    const float* c = com + (size_t)b * COMW;
    float s = 0.f;
#pragma unroll
    for (int i = 0; i < 32; i++) {
        int k = lane + 64 * i;
        s += c[k] * w[k];
    }
#pragma unroll
    for (int off = 32; off > 0; off >>= 1) s += __shfl_down(s, off, 64);
    if (lane == 0) out[b * T_ + t] = s + lin2_b[t];
}

// ---------------------------------------------------------------------------
extern "C" void kernel_launch(void* const* d_in, const int* in_sizes, int n_in,
                              void* d_out, int out_size, void* d_ws, size_t ws_size,
                              hipStream_t stream) {
    const int*   context = (const int*)d_in[0];
    const int*   sidx    = (const int*)d_in[1];
    const int*   oidx    = (const int*)d_in[2];
    const int*   sdis    = (const int*)d_in[3];
    const int*   odis    = (const int*)d_in[4];
    const float* etab    = (const float*)d_in[5];
    const float* ptab    = (const float*)d_in[6];
    const float* conv_w  = (const float*)d_in[7];
    const float* conv_b  = (const float*)d_in[8];
    const float* lin1_w  = (const float*)d_in[9];
    const float* lin1_b  = (const float*)d_in[10];
    const float* lin2_w  = (const float*)d_in[11];
    const float* lin2_b  = (const float*)d_in[12];
    float* out = (float*)d_out;

    char* ws = (char*)d_ws;
    size_t off = 0;
    unsigned char* embp = (unsigned char*)(ws + off);
    off += (size_t)B_ * LE * E_;                 // 8.45 MB (fp8)
    off = (off + 255) & ~(size_t)255;
    unsigned char* posp = (unsigned char*)(ws + off);
    off += (size_t)B_ * LPP * 128;               // 4.2 MB (fp8)
    off = (off + 255) & ~(size_t)255;
    unsigned char* wce = (unsigned char*)(ws + off);
    off += (size_t)5 * KOUT * E_;                // 655 KB (fp8)
    off = (off + 255) & ~(size_t)255;
    unsigned char* wcp = (unsigned char*)(ws + off);
    off += (size_t)3 * KOUT * 128;               // 197 KB (fp8)
    off = (off + 255) & ~(size_t)255;
    __hip_bfloat16* wcorr = (__hip_bfloat16*)(ws + off);
    off += (size_t)2 * KOUT * E_ * 2;            // 0.5 MB
    off = (off + 255) & ~(size_t)255;
    float* corr = (float*)(ws + off);
    off += (size_t)B_ * 2 * KOUT * 4;            // 256 KB
    off = (off + 255) & ~(size_t)255;
    unsigned* pooled = (unsigned*)(ws + off);
    off += (size_t)B_ * KOUT * 4;                // 128 KB
    off = (off + 255) & ~(size_t)255;
    float* com = (float*)(ws + off);
    off += (size_t)B_ * COMW * 4;                // 512 KB

    prep<<<dim3(SEC_END), dim3(256), 0, stream>>>(
        conv_w, context, sidx, oidx, sdis, odis, etab, ptab,
        wce, wcp, wcorr, embp, posp, com, pooled);
    corr_k<<<dim3(4096), dim3(256), 0, stream>>>(context, etab, wcorr, corr);
    conv_gemm_pool<<<dim3(256, 4), dim3(256), 0, stream>>>(embp, posp, wce, wcp, corr, pooled);
    lin1_k<<<dim3(8192), dim3(256), 0, stream>>>(pooled, conv_b, lin1_w, lin1_b, com);
    lin2_k<<<dim3(B_, 14), dim3(256), 0, stream>>>(com, lin2_w, lin2_b, out);
}